// Round 9
// baseline (247.948 us; speedup 1.0000x reference)
//
#include <hip/hip_runtime.h>
#include <hip/hip_bf16.h>

#define N_NODES 50000
#define N_EDGES 600000
#define D 128
#define K2 256  // 2*D
#define SCAN_BLK 1024
#define NB_SCAN ((N_NODES + SCAN_BLK - 1) / SCAN_BLK)  // 49

// fused-prep block ranges
#define CVT_BLOCKS  (N_NODES * 16 / 256)                 // 3125
#define HIST_BLOCKS ((N_EDGES + 255) / 256)              // 2344
#define PREPW_BLOCKS (2 * D * K2 / 256)                  // 256
#define PREP_GRID (CVT_BLOCKS + HIST_BLOCKS + PREPW_BLOCKS)

#define AS_STRIDE 33   // uint4 stride pad: LDS write aliasing <=2-way (free per m136)

typedef __bf16 bf16x8 __attribute__((ext_vector_type(8)));
typedef float  f32x16 __attribute__((ext_vector_type(16)));

__device__ __forceinline__ unsigned short f32_to_bf16_rne(float f) {
    unsigned int u = __builtin_bit_cast(unsigned int, f);
    unsigned int r = (u + 0x7fffu + ((u >> 16) & 1u)) >> 16;
    return (unsigned short)r;
}
__device__ __forceinline__ unsigned pk2(float lo, float hi) {
    return (unsigned)f32_to_bf16_rne(lo) | ((unsigned)f32_to_bf16_rne(hi) << 16);
}
__device__ __forceinline__ float bfl(unsigned int u) { return __builtin_bit_cast(float, u << 16); }
__device__ __forceinline__ float bfh(unsigned int u) { return __builtin_bit_cast(float, u & 0xffff0000u); }

__device__ __forceinline__ void acc8(float* a, uint4 v) {
    a[0] += bfl(v.x); a[1] += bfh(v.x); a[2] += bfl(v.y); a[3] += bfh(v.y);
    a[4] += bfl(v.z); a[5] += bfh(v.z); a[6] += bfl(v.w); a[7] += bfh(v.w);
}

// ---------- fused prep: x->bf16 A0 | edge histogram | W->WT bf16 ----------
__global__ __launch_bounds__(256) void prep_kernel(
    const float* __restrict__ x, const int* __restrict__ ei,
    const float* __restrict__ Wl1, const float* __restrict__ Wr1,
    const float* __restrict__ Wl2, const float* __restrict__ Wr2,
    unsigned short* __restrict__ A0, unsigned short* __restrict__ WT,
    int* __restrict__ counts)
{
    const int b = blockIdx.x;
    if (b < CVT_BLOCKS) {
        int idx = b * 256 + threadIdx.x;       // 800000 exactly
        int node = idx >> 4, g = idx & 15;
        const float4* xp = (const float4*)(x + (size_t)node * D + g * 8);
        float4 v0 = xp[0], v1 = xp[1];
        uint4 o;
        o.x = pk2(v0.x, v0.y); o.y = pk2(v0.z, v0.w);
        o.z = pk2(v1.x, v1.y); o.w = pk2(v1.z, v1.w);
        ((uint4*)A0)[(size_t)node * 16 + g] = o;
    } else if (b < CVT_BLOCKS + HIST_BLOCKS) {
        int e = (b - CVT_BLOCKS) * 256 + threadIdx.x;
        if (e < N_EDGES) atomicAdd(&counts[ei[N_EDGES + e]], 1);
    } else {
        // WT[layer][n][k]: k<128 -> Wl[k][n], k>=128 -> Wr[k-128][n]
        int idx = (b - CVT_BLOCKS - HIST_BLOCKS) * 256 + threadIdx.x;  // 65536 exactly
        int layer = idx >> 15, rem = idx & 32767;
        int n = rem >> 8, k = rem & 255;
        const float* Wl = layer ? Wl2 : Wl1;
        const float* Wr = layer ? Wr2 : Wr1;
        float v = (k < D) ? Wl[k * D + n] : Wr[(k - D) * D + n];
        WT[((size_t)layer << 15) + n * K2 + k] = f32_to_bf16_rne(v);
    }
}

// ---- scan phase 1: per-block sums (256 thr x 4 elems) ----
__global__ __launch_bounds__(256) void scan_p1(const int* __restrict__ counts,
                                               int* __restrict__ bsum) {
    __shared__ int wsum[4];
    const int tid = threadIdx.x;
    const int lane = tid & 63, wid = tid >> 6;
    int i0 = blockIdx.x * SCAN_BLK + tid * 4;
    int t = 0;
    #pragma unroll
    for (int k = 0; k < 4; ++k) if (i0 + k < N_NODES) t += counts[i0 + k];
    int acc = t;
    #pragma unroll
    for (int d = 1; d < 64; d <<= 1) {
        int v = __shfl_up(acc, d, 64);
        if (lane >= d) acc += v;
    }
    if (lane == 63) wsum[wid] = acc;
    __syncthreads();
    if (tid == 0) bsum[blockIdx.x] = wsum[0] + wsum[1] + wsum[2] + wsum[3];
}

// ---- scan phase 2+3 fused: each block sums its predecessors' bsums itself ----
__global__ __launch_bounds__(256) void scan_p3(int* __restrict__ counts,
                                               const int* __restrict__ bsum,
                                               int* __restrict__ offsets) {
    __shared__ int wsum[4];
    __shared__ int bpre_s;
    const int tid = threadIdx.x;
    const int lane = tid & 63, wid = tid >> 6;
    if (tid < 64) {
        int v = (tid < blockIdx.x) ? bsum[tid] : 0;   // NB_SCAN=49 <= 64
        #pragma unroll
        for (int d = 32; d; d >>= 1) v += __shfl_xor(v, d, 64);
        if (tid == 0) bpre_s = v;
    }
    int i0 = blockIdx.x * SCAN_BLK + tid * 4;
    int c[4];
    int t = 0;
    #pragma unroll
    for (int k = 0; k < 4; ++k) {
        c[k] = (i0 + k < N_NODES) ? counts[i0 + k] : 0;
        t += c[k];
    }
    int acc = t;
    #pragma unroll
    for (int d = 1; d < 64; d <<= 1) {
        int v = __shfl_up(acc, d, 64);
        if (lane >= d) acc += v;
    }
    if (lane == 63) wsum[wid] = acc;
    __syncthreads();
    if (tid == 0) {
        int s = 0;
        #pragma unroll
        for (int w = 0; w < 4; ++w) { int v = wsum[w]; wsum[w] = s; s += v; }
    }
    __syncthreads();
    int excl = bpre_s + wsum[wid] + (acc - t);
    #pragma unroll
    for (int k = 0; k < 4; ++k) {
        if (i0 + k < N_NODES) {
            counts[i0 + k] = excl;              // scatter cursor
            offsets[i0 + k + 1] = excl + c[k];  // segment end
        }
        excl += c[k];
    }
    if (blockIdx.x == 0 && tid == 0) offsets[0] = 0;
}

__global__ __launch_bounds__(256) void build_csr_kernel(const int* __restrict__ ei,
                                                        int* __restrict__ cursor,
                                                        int* __restrict__ sorted_src) {
    int e = blockIdx.x * blockDim.x + threadIdx.x;
    if (e < N_EDGES) {
        int src = ei[e];
        int dst = ei[N_EDGES + e];
        int pos = atomicAdd(&cursor[dst], 1);
        sorted_src[pos] = src;
    }
}

// ---------- fused layer: gather-mean -> LDS A-tile (fragment order) -> MFMA ----------
// Block = 256 thr, 32 nodes. As4[slot*AS_STRIDE + m] holds A[m][slot*8 .. slot*8+7]:
// slots 0..15 = mean half (k<128), 16..31 = self-x half. Gather: 16 lanes/node,
// one uint4 per lane per edge (fully-coalesced 256 B per edge). The two node-halves
// per thread are software-pipelined TOGETHER: 8 independent row loads in flight.
// GEMM: wave w -> cols [w*32,w*32+32), K=256.
// C/D: col=lane&31, row=(reg&3)+8*(reg>>2)+4*(lane>>5)  [measured m74/m101].
template <bool RELU, bool OUT_BF16>
__global__ __launch_bounds__(256) void layer_kernel(
    const unsigned short* __restrict__ Xin,   // [N][128] bf16
    const int* __restrict__ offsets, const int* __restrict__ srcs,
    const unsigned short* __restrict__ WT,    // [128][256] bf16
    const float* __restrict__ bias,
    unsigned short* __restrict__ Hout,        // layer1: h bf16 [N][128]
    float* __restrict__ outf)                 // layer2: f32 [N][128]
{
    __shared__ uint4 As4[32 * AS_STRIDE];      // 16.9 KB
    const int tid = threadIdx.x;
    const int base = blockIdx.x * 32;
    const uint4* X4 = (const uint4*)Xin;       // row stride = 16 uint4

    // ---- gather phase ----
    {
        const int c  = tid & 15;               // 16B chunk within row
        const int m0 = tid >> 4;               // 0..15
        const int nodeA = base + m0;
        const int nodeB = base + m0 + 16;
        int begA = 0, endA = 0, begB = 0, endB = 0;
        if (nodeA < N_NODES) { begA = offsets[nodeA]; endA = offsets[nodeA + 1]; }
        if (nodeB < N_NODES) { begB = offsets[nodeB]; endB = offsets[nodeB + 1]; }

        float aA[8], aB[8];
        #pragma unroll
        for (int k = 0; k < 8; ++k) { aA[k] = 0.0f; aB[k] = 0.0f; }

        int eA = begA, eB = begB;

        // joint pipelined loop: 8 row loads issued before any consume
        while (eA + 3 < endA && eB + 3 < endB) {
            int sA0 = srcs[eA], sA1 = srcs[eA + 1], sA2 = srcs[eA + 2], sA3 = srcs[eA + 3];
            int sB0 = srcs[eB], sB1 = srcs[eB + 1], sB2 = srcs[eB + 2], sB3 = srcs[eB + 3];
            uint4 vA0 = X4[(size_t)sA0 * 16 + c];
            uint4 vA1 = X4[(size_t)sA1 * 16 + c];
            uint4 vA2 = X4[(size_t)sA2 * 16 + c];
            uint4 vA3 = X4[(size_t)sA3 * 16 + c];
            uint4 vB0 = X4[(size_t)sB0 * 16 + c];
            uint4 vB1 = X4[(size_t)sB1 * 16 + c];
            uint4 vB2 = X4[(size_t)sB2 * 16 + c];
            uint4 vB3 = X4[(size_t)sB3 * 16 + c];
            acc8(aA, vA0); acc8(aA, vA1); acc8(aA, vA2); acc8(aA, vA3);
            acc8(aB, vB0); acc8(aB, vB1); acc8(aB, vB2); acc8(aB, vB3);
            eA += 4; eB += 4;
        }
        // drains (keep per-node edge order -> bit-identical results)
        for (; eA + 3 < endA; eA += 4) {
            int s0 = srcs[eA], s1 = srcs[eA + 1], s2 = srcs[eA + 2], s3 = srcs[eA + 3];
            uint4 v0 = X4[(size_t)s0 * 16 + c];
            uint4 v1 = X4[(size_t)s1 * 16 + c];
            uint4 v2 = X4[(size_t)s2 * 16 + c];
            uint4 v3 = X4[(size_t)s3 * 16 + c];
            acc8(aA, v0); acc8(aA, v1); acc8(aA, v2); acc8(aA, v3);
        }
        for (; eA < endA; ++eA) acc8(aA, X4[(size_t)srcs[eA] * 16 + c]);
        for (; eB + 3 < endB; eB += 4) {
            int s0 = srcs[eB], s1 = srcs[eB + 1], s2 = srcs[eB + 2], s3 = srcs[eB + 3];
            uint4 v0 = X4[(size_t)s0 * 16 + c];
            uint4 v1 = X4[(size_t)s1 * 16 + c];
            uint4 v2 = X4[(size_t)s2 * 16 + c];
            uint4 v3 = X4[(size_t)s3 * 16 + c];
            acc8(aB, v0); acc8(aB, v1); acc8(aB, v2); acc8(aB, v3);
        }
        for (; eB < endB; ++eB) acc8(aB, X4[(size_t)srcs[eB] * 16 + c]);

        float invA = 1.0f / fmaxf((float)(endA - begA), 1.0f);
        float invB = 1.0f / fmaxf((float)(endB - begB), 1.0f);
        uint4 oA, oB;
        oA.x = pk2(aA[0] * invA, aA[1] * invA); oA.y = pk2(aA[2] * invA, aA[3] * invA);
        oA.z = pk2(aA[4] * invA, aA[5] * invA); oA.w = pk2(aA[6] * invA, aA[7] * invA);
        oB.x = pk2(aB[0] * invB, aB[1] * invB); oB.y = pk2(aB[2] * invB, aB[3] * invB);
        oB.z = pk2(aB[4] * invB, aB[5] * invB); oB.w = pk2(aB[6] * invB, aB[7] * invB);
        As4[c * AS_STRIDE + m0]        = oA;           // mean half: slot c
        As4[c * AS_STRIDE + m0 + 16]   = oB;
        uint4 xA = {0, 0, 0, 0}, xB = {0, 0, 0, 0};
        if (nodeA < N_NODES) xA = X4[(size_t)nodeA * 16 + c];
        if (nodeB < N_NODES) xB = X4[(size_t)nodeB * 16 + c];
        As4[(16 + c) * AS_STRIDE + m0]      = xA;      // x half: slot 16+c
        As4[(16 + c) * AS_STRIDE + m0 + 16] = xB;
    }
    __syncthreads();

    // ---- GEMM phase ----
    const int l = tid & 63;
    const int w = tid >> 6;
    const int m = l & 31;
    const int kg = l >> 5;
    const int col = w * 32 + m;
    const uint4* bp = (const uint4*)(WT + (size_t)col * K2 + kg * 8);
    const bf16x8* afrag = (const bf16x8*)As4;

    f32x16 acc = {};
    #pragma unroll
    for (int s = 0; s < 16; ++s) {
        bf16x8 a = afrag[(s * 2 + kg) * AS_STRIDE + m];
        bf16x8 b = __builtin_bit_cast(bf16x8, bp[s * 2]);
        acc = __builtin_amdgcn_mfma_f32_32x32x16_bf16(a, b, acc, 0, 0, 0);
    }

    const float bc = bias[col];
    const int halfadd = kg * 4;
    #pragma unroll
    for (int r = 0; r < 16; ++r) {
        int rw = base + (r & 3) + 8 * (r >> 2) + halfadd;
        if (rw < N_NODES) {
            float v = acc[r] + bc;
            if (RELU) v = fmaxf(v, 0.0f);
            if (OUT_BF16) Hout[(size_t)rw * D + col] = f32_to_bf16_rne(v);
            else outf[(size_t)rw * D + col] = v;
        }
    }
}

extern "C" void kernel_launch(void* const* d_in, const int* in_sizes, int n_in,
                              void* d_out, int out_size, void* d_ws, size_t ws_size,
                              hipStream_t stream) {
    const float* x   = (const float*)d_in[0];
    const int*   ei  = (const int*)d_in[1];
    const float* Wl1 = (const float*)d_in[2];
    const float* Wr1 = (const float*)d_in[3];
    const float* b1  = (const float*)d_in[4];
    const float* Wl2 = (const float*)d_in[5];
    const float* Wr2 = (const float*)d_in[6];
    const float* b2  = (const float*)d_in[7];
    float* out = (float*)d_out;

    // ws: A0 [N][128] bf16 | A1 [N][128] bf16 | WT [2][128][256] bf16 |
    //     counts [N] | offsets [N+1] | srcs [E] | bsum [64]
    unsigned short* A0 = (unsigned short*)d_ws;
    unsigned short* A1 = A0 + (size_t)N_NODES * D;
    unsigned short* WT = A1 + (size_t)N_NODES * D;
    int* counts  = (int*)(WT + 2 * D * K2);
    int* offsets = counts + N_NODES;
    int* srcs    = offsets + N_NODES + 1;
    int* bsum    = srcs + N_EDGES;

    const int layerBlocks = (N_NODES + 31) / 32;  // 1563

    hipMemsetAsync(counts, 0, N_NODES * sizeof(int), stream);
    prep_kernel<<<PREP_GRID, 256, 0, stream>>>(x, ei, Wl1, Wr1, Wl2, Wr2, A0, WT, counts);
    scan_p1<<<NB_SCAN, 256, 0, stream>>>(counts, bsum);
    scan_p3<<<NB_SCAN, 256, 0, stream>>>(counts, bsum, offsets);
    build_csr_kernel<<<HIST_BLOCKS, 256, 0, stream>>>(ei, counts, srcs);

    layer_kernel<true, true><<<layerBlocks, 256, 0, stream>>>(
        A0, offsets, srcs, WT, b1, A1, nullptr);
    layer_kernel<false, false><<<layerBlocks, 256, 0, stream>>>(
        A1, offsets, srcs, WT + (size_t)D * K2, b2, nullptr, out);
}

// Round 10
// 240.706 us; speedup vs baseline: 1.0301x; 1.0301x over previous
//
#include <hip/hip_runtime.h>
#include <hip/hip_bf16.h>

#define N_NODES 50000
#define N_EDGES 600000
#define D 128
#define K2 256  // 2*D
#define SCAN_BLK 1024
#define NB_SCAN ((N_NODES + SCAN_BLK - 1) / SCAN_BLK)  // 49

// fused-prep block ranges
#define CVT_BLOCKS  (N_NODES * 16 / 256)                 // 3125
#define HIST_BLOCKS ((N_EDGES + 255) / 256)              // 2344
#define PREPW_BLOCKS (2 * D * K2 / 256)                  // 256
#define PREP_GRID (CVT_BLOCKS + HIST_BLOCKS + PREPW_BLOCKS)

#define AS_STRIDE 33   // uint4 stride pad: LDS aliasing <=2-way (free per m136)

typedef __bf16 bf16x8 __attribute__((ext_vector_type(8)));
typedef float  f32x16 __attribute__((ext_vector_type(16)));

__device__ __forceinline__ unsigned short f32_to_bf16_rne(float f) {
    unsigned int u = __builtin_bit_cast(unsigned int, f);
    unsigned int r = (u + 0x7fffu + ((u >> 16) & 1u)) >> 16;
    return (unsigned short)r;
}
__device__ __forceinline__ unsigned pk2(float lo, float hi) {
    return (unsigned)f32_to_bf16_rne(lo) | ((unsigned)f32_to_bf16_rne(hi) << 16);
}
__device__ __forceinline__ float bfl(unsigned int u) { return __builtin_bit_cast(float, u << 16); }
__device__ __forceinline__ float bfh(unsigned int u) { return __builtin_bit_cast(float, u & 0xffff0000u); }

__device__ __forceinline__ void acc8(float* a, uint4 v) {
    a[0] += bfl(v.x); a[1] += bfh(v.x); a[2] += bfl(v.y); a[3] += bfh(v.y);
    a[4] += bfl(v.z); a[5] += bfh(v.z); a[6] += bfl(v.w); a[7] += bfh(v.w);
}

// ---------- fused prep: x->bf16 A0 | edge histogram | W->WT bf16 ----------
__global__ __launch_bounds__(256) void prep_kernel(
    const float* __restrict__ x, const int* __restrict__ ei,
    const float* __restrict__ Wl1, const float* __restrict__ Wr1,
    const float* __restrict__ Wl2, const float* __restrict__ Wr2,
    unsigned short* __restrict__ A0, unsigned short* __restrict__ WT,
    int* __restrict__ counts)
{
    const int b = blockIdx.x;
    if (b < CVT_BLOCKS) {
        int idx = b * 256 + threadIdx.x;       // 800000 exactly
        int node = idx >> 4, g = idx & 15;
        const float4* xp = (const float4*)(x + (size_t)node * D + g * 8);
        float4 v0 = xp[0], v1 = xp[1];
        uint4 o;
        o.x = pk2(v0.x, v0.y); o.y = pk2(v0.z, v0.w);
        o.z = pk2(v1.x, v1.y); o.w = pk2(v1.z, v1.w);
        ((uint4*)A0)[(size_t)node * 16 + g] = o;
    } else if (b < CVT_BLOCKS + HIST_BLOCKS) {
        int e = (b - CVT_BLOCKS) * 256 + threadIdx.x;
        if (e < N_EDGES) atomicAdd(&counts[ei[N_EDGES + e]], 1);
    } else {
        // WT[layer][n][k]: k<128 -> Wl[k][n], k>=128 -> Wr[k-128][n]
        int idx = (b - CVT_BLOCKS - HIST_BLOCKS) * 256 + threadIdx.x;  // 65536 exactly
        int layer = idx >> 15, rem = idx & 32767;
        int n = rem >> 8, k = rem & 255;
        const float* Wl = layer ? Wl2 : Wl1;
        const float* Wr = layer ? Wr2 : Wr1;
        float v = (k < D) ? Wl[k * D + n] : Wr[(k - D) * D + n];
        WT[((size_t)layer << 15) + n * K2 + k] = f32_to_bf16_rne(v);
    }
}

// ---- scan phase 1: per-block sums (256 thr x 4 elems) ----
__global__ __launch_bounds__(256) void scan_p1(const int* __restrict__ counts,
                                               int* __restrict__ bsum) {
    __shared__ int wsum[4];
    const int tid = threadIdx.x;
    const int lane = tid & 63, wid = tid >> 6;
    int i0 = blockIdx.x * SCAN_BLK + tid * 4;
    int t = 0;
    #pragma unroll
    for (int k = 0; k < 4; ++k) if (i0 + k < N_NODES) t += counts[i0 + k];
    int acc = t;
    #pragma unroll
    for (int d = 1; d < 64; d <<= 1) {
        int v = __shfl_up(acc, d, 64);
        if (lane >= d) acc += v;
    }
    if (lane == 63) wsum[wid] = acc;
    __syncthreads();
    if (tid == 0) bsum[blockIdx.x] = wsum[0] + wsum[1] + wsum[2] + wsum[3];
}

// ---- scan phase 2+3 fused: each block sums its predecessors' bsums itself ----
__global__ __launch_bounds__(256) void scan_p3(int* __restrict__ counts,
                                               const int* __restrict__ bsum,
                                               int* __restrict__ offsets) {
    __shared__ int wsum[4];
    __shared__ int bpre_s;
    const int tid = threadIdx.x;
    const int lane = tid & 63, wid = tid >> 6;
    if (tid < 64) {
        int v = (tid < blockIdx.x) ? bsum[tid] : 0;   // NB_SCAN=49 <= 64
        #pragma unroll
        for (int d = 32; d; d >>= 1) v += __shfl_xor(v, d, 64);
        if (tid == 0) bpre_s = v;
    }
    int i0 = blockIdx.x * SCAN_BLK + tid * 4;
    int c[4];
    int t = 0;
    #pragma unroll
    for (int k = 0; k < 4; ++k) {
        c[k] = (i0 + k < N_NODES) ? counts[i0 + k] : 0;
        t += c[k];
    }
    int acc = t;
    #pragma unroll
    for (int d = 1; d < 64; d <<= 1) {
        int v = __shfl_up(acc, d, 64);
        if (lane >= d) acc += v;
    }
    if (lane == 63) wsum[wid] = acc;
    __syncthreads();
    if (tid == 0) {
        int s = 0;
        #pragma unroll
        for (int w = 0; w < 4; ++w) { int v = wsum[w]; wsum[w] = s; s += v; }
    }
    __syncthreads();
    int excl = bpre_s + wsum[wid] + (acc - t);
    #pragma unroll
    for (int k = 0; k < 4; ++k) {
        if (i0 + k < N_NODES) {
            counts[i0 + k] = excl;              // scatter cursor
            offsets[i0 + k + 1] = excl + c[k];  // segment end
        }
        excl += c[k];
    }
    if (blockIdx.x == 0 && tid == 0) offsets[0] = 0;
}

__global__ __launch_bounds__(256) void build_csr_kernel(const int* __restrict__ ei,
                                                        int* __restrict__ cursor,
                                                        int* __restrict__ sorted_src) {
    int e = blockIdx.x * blockDim.x + threadIdx.x;
    if (e < N_EDGES) {
        int src = ei[e];
        int dst = ei[N_EDGES + e];
        int pos = atomicAdd(&cursor[dst], 1);
        sorted_src[pos] = src;
    }
}

// ---------- fused layer: wave-per-node gather-mean -> LDS A-tile -> MFMA ----------
// Block = 256 thr (4 waves), 32 nodes. Wave w processes nodes base+w*8 .. +7
// SEQUENTIALLY; for one node all 64 lanes cooperate: lane = chunk c (0..15) x
// edge-slot j (0..3); loop e = beg+j, step 4 -> every trip is one fully-coalesced
// 4x256B wave read, offsets are wave-uniform (scalar), divergence <= 1 iteration.
// Cross-slot reduce: shfl_xor 16,32. LDS As4[slot*AS_STRIDE+m]: slots 0..15 mean,
// 16..31 self-x. GEMM: wave w -> cols [w*32,w*32+32), K=256, MFMA 32x32x16.
// C/D: col=lane&31, row=(reg&3)+8*(reg>>2)+4*(lane>>5)  [measured m74/m101].
template <bool RELU, bool OUT_BF16>
__global__ __launch_bounds__(256) void layer_kernel(
    const unsigned short* __restrict__ Xin,   // [N][128] bf16
    const int* __restrict__ offsets, const int* __restrict__ srcs,
    const unsigned short* __restrict__ WT,    // [128][256] bf16
    const float* __restrict__ bias,
    unsigned short* __restrict__ Hout,        // layer1: h bf16 [N][128]
    float* __restrict__ outf)                 // layer2: f32 [N][128]
{
    __shared__ uint4 As4[32 * AS_STRIDE];      // 16.9 KB
    const int tid = threadIdx.x;
    const int base = blockIdx.x * 32;
    const uint4* X4 = (const uint4*)Xin;       // row stride = 16 uint4

    // ---- gather phase: wave-per-node ----
    {
        const int w = tid >> 6;                // wave 0..3
        const int lane = tid & 63;
        const int c = lane & 15;               // 16B chunk within row
        const int j = lane >> 4;               // edge slot 0..3

        #pragma unroll
        for (int i = 0; i < 8; ++i) {
            const int m = w * 8 + i;           // node slot in tile
            const int node = base + m;         // wave-uniform
            int beg = 0, end = 0;
            if (node < N_NODES) { beg = offsets[node]; end = offsets[node + 1]; }

            float a[8];
            #pragma unroll
            for (int k = 0; k < 8; ++k) a[k] = 0.0f;

            for (int e = beg + j; e < end; e += 4)
                acc8(a, X4[(size_t)srcs[e] * 16 + c]);

            // reduce the 4 edge-slot partials (lanes c, c+16, c+32, c+48)
            #pragma unroll
            for (int k = 0; k < 8; ++k) {
                a[k] += __shfl_xor(a[k], 16, 64);
                a[k] += __shfl_xor(a[k], 32, 64);
            }

            if (j == 0) {
                float inv = 1.0f / fmaxf((float)(end - beg), 1.0f);
                uint4 o;
                o.x = pk2(a[0] * inv, a[1] * inv); o.y = pk2(a[2] * inv, a[3] * inv);
                o.z = pk2(a[4] * inv, a[5] * inv); o.w = pk2(a[6] * inv, a[7] * inv);
                As4[c * AS_STRIDE + m] = o;                  // mean half: slot c
            } else if (j == 1) {
                uint4 xv = {0, 0, 0, 0};
                if (node < N_NODES) xv = X4[(size_t)node * 16 + c];
                As4[(16 + c) * AS_STRIDE + m] = xv;          // x half: slot 16+c
            }
        }
    }
    __syncthreads();

    // ---- GEMM phase ----
    const int l = tid & 63;
    const int w = tid >> 6;
    const int m = l & 31;
    const int kg = l >> 5;
    const int col = w * 32 + m;
    const uint4* bp = (const uint4*)(WT + (size_t)col * K2 + kg * 8);
    const bf16x8* afrag = (const bf16x8*)As4;

    f32x16 acc = {};
    #pragma unroll
    for (int s = 0; s < 16; ++s) {
        bf16x8 a = afrag[(s * 2 + kg) * AS_STRIDE + m];
        bf16x8 b = __builtin_bit_cast(bf16x8, bp[s * 2]);
        acc = __builtin_amdgcn_mfma_f32_32x32x16_bf16(a, b, acc, 0, 0, 0);
    }

    const float bc = bias[col];
    const int halfadd = kg * 4;
    #pragma unroll
    for (int r = 0; r < 16; ++r) {
        int rw = base + (r & 3) + 8 * (r >> 2) + halfadd;
        if (rw < N_NODES) {
            float v = acc[r] + bc;
            if (RELU) v = fmaxf(v, 0.0f);
            if (OUT_BF16) Hout[(size_t)rw * D + col] = f32_to_bf16_rne(v);
            else outf[(size_t)rw * D + col] = v;
        }
    }
}

extern "C" void kernel_launch(void* const* d_in, const int* in_sizes, int n_in,
                              void* d_out, int out_size, void* d_ws, size_t ws_size,
                              hipStream_t stream) {
    const float* x   = (const float*)d_in[0];
    const int*   ei  = (const int*)d_in[1];
    const float* Wl1 = (const float*)d_in[2];
    const float* Wr1 = (const float*)d_in[3];
    const float* b1  = (const float*)d_in[4];
    const float* Wl2 = (const float*)d_in[5];
    const float* Wr2 = (const float*)d_in[6];
    const float* b2  = (const float*)d_in[7];
    float* out = (float*)d_out;

    // ws: A0 [N][128] bf16 | A1 [N][128] bf16 | WT [2][128][256] bf16 |
    //     counts [N] | offsets [N+1] | srcs [E] | bsum [64]
    unsigned short* A0 = (unsigned short*)d_ws;
    unsigned short* A1 = A0 + (size_t)N_NODES * D;
    unsigned short* WT = A1 + (size_t)N_NODES * D;
    int* counts  = (int*)(WT + 2 * D * K2);
    int* offsets = counts + N_NODES;
    int* srcs    = offsets + N_NODES + 1;
    int* bsum    = srcs + N_EDGES;

    const int layerBlocks = (N_NODES + 31) / 32;  // 1563

    hipMemsetAsync(counts, 0, N_NODES * sizeof(int), stream);
    prep_kernel<<<PREP_GRID, 256, 0, stream>>>(x, ei, Wl1, Wr1, Wl2, Wr2, A0, WT, counts);
    scan_p1<<<NB_SCAN, 256, 0, stream>>>(counts, bsum);
    scan_p3<<<NB_SCAN, 256, 0, stream>>>(counts, bsum, offsets);
    build_csr_kernel<<<HIST_BLOCKS, 256, 0, stream>>>(ei, counts, srcs);

    layer_kernel<true, true><<<layerBlocks, 256, 0, stream>>>(
        A0, offsets, srcs, WT, b1, A1, nullptr);
    layer_kernel<false, false><<<layerBlocks, 256, 0, stream>>>(
        A1, offsets, srcs, WT + (size_t)D * K2, b2, nullptr, out);
}